// Round 4
// baseline (492.326 us; speedup 1.0000x reference)
//
#include <hip/hip_runtime.h>

typedef unsigned long long u64;
typedef unsigned int u32;

#define N0 147456   // 384*384
#define N1 36864    // 192*192
#define NTOT 184320 // = 720 * 256 exactly
#define NBLK 720    // cand blocks per slot
#define KKP 512
#define KM 128
#define NBINS 16384
#define CAP_COL 2048
#define BIN12 4096      // gemm block-local histogram bins (key32 >> 20)
#define SEG_MC 4096     // per-gemm-block match-candidate segment (worst case = all 4096)

struct InPtrs {
  const float* rep[2][2];   // [img][level]
  const float* rel[2][2];
  const float* desc[2][2];
};

// ---------------- candidate generation ----------------
// slot = img*2 + b. Key = (score_bits<<32) | ~pixel_index  ->  descending sort
// == descending score, ties broken by LOWER index (matches lax.top_k).
// Per-block PRIVATE segment output: no global atomics, no pre-zeroed counters
// (R3 post-mortem: each stream node costs ~10-20us; killing the counter memset
// node requires every count be written unconditionally).
__global__ __launch_bounds__(256) void cand_kernel(InPtrs P, u64* __restrict__ cand,
                                                   int* __restrict__ cnt_blk) {
  __shared__ u64 buf[256];
  __shared__ int lcnt;
  int slot = blockIdx.y;
  int img = slot >> 1, b = slot & 1;
  int p = blockIdx.x * 256 + threadIdx.x;   // NTOT == 720*256, no tail
  if (threadIdx.x == 0) lcnt = 0;
  __syncthreads();
  int level, W, q, Npix;
  if (p < N0) { level = 0; W = 384; q = p; Npix = N0; }
  else        { level = 1; W = 192; q = p - N0; Npix = N1; }
  const float* rp = P.rep[img][level] + (size_t)b * Npix;
  const float* rl = P.rel[img][level] + (size_t)b * Npix;
  float v = rp[q];
  float m = sqrtf(v * rl[q]);
  bool ok = (m >= 0.7f);
  if (ok) {
    int y = q / W, x = q - y * W;   // square levels: H == W
    int y0 = (y > 0) ? y - 1 : y, y1 = (y < W - 1) ? y + 1 : y;
    int x0 = (x > 0) ? x - 1 : x, x1 = (x < W - 1) ? x + 1 : x;
    for (int yy = y0; yy <= y1 && ok; ++yy)
      for (int xx = x0; xx <= x1; ++xx)
        if (rp[yy * W + xx] > v) { ok = false; break; }
  }
  if (ok) {
    u32 sb = __float_as_uint(m);
    int pos = atomicAdd(&lcnt, 1);          // LDS atomic only
    buf[pos] = ((u64)sb << 32) | (u32)(~(u32)p);
  }
  __syncthreads();
  int n = lcnt;
  if (threadIdx.x == 0) cnt_blk[slot * NBLK + blockIdx.x] = n;
  if ((int)threadIdx.x < n)
    cand[(size_t)slot * NTOT + blockIdx.x * 256 + threadIdx.x] = buf[threadIdx.x];
}

// ------- adaptive bitonic sort of n (pow2) u64 keys in LDS, descending -------
__device__ inline void bitonicN(u64* k, int t, int n, int nthreads) {
  for (int size = 2; size <= n; size <<= 1) {
    for (int j = size >> 1; j > 0; j >>= 1) {
      __syncthreads();
      for (int i = t; i < n; i += nthreads) {
        int ixj = i ^ j;
        if (ixj > i) {
          u64 a = k[i], b = k[ixj];
          bool desc = ((i & size) == 0);
          if (desc ? (a < b) : (a > b)) { k[i] = b; k[ixj] = a; }
        }
      }
    }
  }
  __syncthreads();
}

// ---------------- keypoint top-512: radix-select + exact sort + decode ----------------
// Streams the ragged per-block segments via a dense virtual sweep (v = blk*256+i);
// selection is by full key value so segment order is irrelevant -> bit-identical.
__global__ __launch_bounds__(1024) void kp_select(const u64* __restrict__ keys_all,
                                                  const int* __restrict__ cnt_blk,
                                                  float* __restrict__ kp_loc,
                                                  int* __restrict__ kp_level,
                                                  int* __restrict__ kp_p,
                                                  float* __restrict__ kp_score) {
  __shared__ int hist[NBINS];
  __shared__ u64 kbuf[CAP_COL];
  __shared__ int part[1024];
  __shared__ int bc[NBLK];
  __shared__ int Bbin, colcnt;
  int slot = blockIdx.x;
  int t = threadIdx.x;
  const u64* keys = keys_all + (size_t)slot * NTOT;
  for (int i = t; i < NBINS; i += 1024) hist[i] = 0;
  if (t < NBLK) bc[t] = cnt_blk[slot * NBLK + t];
  if (t == 0) { Bbin = 0; colcnt = 0; }
  __syncthreads();
  for (int v = t; v < NTOT; v += 1024) {      // 180 iters; count check is LDS broadcast
    int blk = v >> 8, i = v & 255;
    if (i < bc[blk]) {
      u32 bin = (u32)((keys[v] >> 41) & (NBINS - 1));
      atomicAdd(&hist[bin], 1);
    }
  }
  __syncthreads();
  const int BPT = NBINS / 1024;
  int base = t * BPT;
  int lsum = 0;
  for (int j = 0; j < BPT; ++j) lsum += hist[base + j];
  part[t] = lsum;
  __syncthreads();
  for (int off = 1; off < 1024; off <<= 1) {   // suffix scan
    int v = (t + off < 1024) ? part[t + off] : 0;
    __syncthreads();
    part[t] += v;
    __syncthreads();
  }
  int Sab = part[t] - lsum;   // count strictly above my bin range
  if (Sab < KKP && Sab + lsum >= KKP) {
    int c = Sab;
    for (int j = BPT - 1; j >= 0; --j) {
      c += hist[base + j];
      if (c >= KKP) { Bbin = base + j; break; }
    }
  }
  __syncthreads();
  int Bb = Bbin;
  for (int v = t; v < NTOT; v += 1024) {
    int blk = v >> 8, i = v & 255;
    if (i < bc[blk]) {
      u64 kk = keys[v];
      if ((int)((kk >> 41) & (NBINS - 1)) >= Bb) {
        int pos = atomicAdd(&colcnt, 1);
        if (pos < CAP_COL) kbuf[pos] = kk;
      }
    }
  }
  __syncthreads();
  int nc = colcnt; if (nc > CAP_COL) nc = CAP_COL;   // nc >= 512 by construction
  int npow = 1; while (npow < nc) npow <<= 1;        // adaptive sort width
  for (int i = t; i < npow; i += 1024) if (i >= nc) kbuf[i] = 0;
  __syncthreads();
  bitonicN(kbuf, t, npow, 1024);
  // fused decode (t < 512)
  if (t < KKP) {
    u64 key = kbuf[t];
    float s = __uint_as_float((u32)(key >> 32));
    u32 idx = ~(u32)key;
    int level, p, W, scale;
    if (idx < N0) { level = 0; p = (int)idx; W = 384; scale = 1; }
    else          { level = 1; p = (int)(idx - N0); W = 192; scale = 2; }
    if (p < 0 || p >= (level ? N1 : N0)) { p = 0; s = 0.f; }  // pad guard
    int y = p / W, x = p - y * W;
    kp_loc[(slot * 2 + 0) * KKP + t] = (float)(y * scale);
    kp_loc[(slot * 2 + 1) * KKP + t] = (float)(x * scale);
    kp_level[slot * KKP + t] = level;
    kp_p[slot * KKP + t] = p;
    kp_score[slot * KKP + t] = s;
  }
}

// ---------------- order-preserving float->u32 key ----------------
__device__ inline u32 fkey32(float v) {
  u32 bits = __float_as_uint(v);
  return (bits & 0x80000000u) ? ~bits : (bits | 0x80000000u);
}

// -------- fp32 GEMM (gather fused) + block-local top-128 candidate select --------
// Staging gathers descriptors DIRECTLY from desc: tA[c][kp] = desc_val * score,
// the exact fp32 expression the old gather_kernel stored to dAt, then the same
// accumulation loop -> bit-identical. Deletes the gather node + dAt round-trip.
// Output via per-block private segment (no atomics, no zeroed counters).
// Local-select exactness: an element with >=128 same-block elements in strictly
// higher bins has >=128 globally-larger keys, so the per-block bin-threshold
// superset contains the global top-128; final select is exact on full keys.
union GemmSmem {
  struct { float tA[128][68]; float tB[128][68]; } g;           // 69,632 B
  struct { int lh[BIN12]; int part[256]; u64 lbuf[4096]; } h;   // 49,408 B
};

__global__ __launch_bounds__(256) void gemm_kernel(InPtrs P,
                                                   const int* __restrict__ kp_level,
                                                   const int* __restrict__ kp_p,
                                                   const float* __restrict__ kp_score,
                                                   u64* __restrict__ mcand,
                                                   int* __restrict__ mcnt_blk) {
  __shared__ GemmSmem sm;
  __shared__ const float* basep[128];   // [0,64): A kps, [64,128): B kps
  __shared__ int strid[128];
  __shared__ float sco[128];
  __shared__ int Bbin, lcnt;
  int b = blockIdx.z;
  int row0 = blockIdx.y * 64, col0 = blockIdx.x * 64;
  int t = threadIdx.y * 16 + threadIdx.x;
  if (t < 128) {
    int isB = t >> 6, kk = t & 63;
    int slot = isB ? (2 + b) : b;                  // img0 slot=b, img1 slot=2+b
    int k = (isB ? col0 : row0) + kk;
    int lvl = kp_level[slot * KKP + k];
    int p = kp_p[slot * KKP + k];
    int img = slot >> 1;
    size_t HW = lvl ? N1 : N0;
    basep[t] = P.desc[img][lvl] + ((size_t)(slot & 1) * 128) * HW + p;
    strid[t] = (int)HW;
    sco[t] = kp_score[slot * KKP + k];
  }
  __syncthreads();
  // gather-staging: i = c*64+kp; lanes cover kp 0..63 (conflict-free LDS stores)
  for (int j = 0; j < 32; ++j) {
    int i = j * 256 + t;
    int kp = i & 63, c = i >> 6;
    sm.g.tA[c][kp] = basep[kp][(size_t)c * strid[kp]] * sco[kp];
  }
  for (int j = 0; j < 32; ++j) {
    int i = j * 256 + t;
    int kp = i & 63, c = i >> 6;
    sm.g.tB[c][kp] = basep[64 + kp][(size_t)c * strid[64 + kp]] * sco[64 + kp];
  }
  __syncthreads();
  float acc[4][4] = {};
  int ra = threadIdx.y * 4, rb = threadIdx.x * 4;
  for (int k = 0; k < 128; ++k) {
    float4 a4 = *(const float4*)&sm.g.tA[k][ra];
    float4 b4 = *(const float4*)&sm.g.tB[k][rb];
    float a[4] = {a4.x, a4.y, a4.z, a4.w};
    float bb[4] = {b4.x, b4.y, b4.z, b4.w};
    for (int i = 0; i < 4; ++i)
      for (int j = 0; j < 4; ++j)
        acc[i][j] += a[i] * bb[j];
  }
  // ---- block-local select (tA/tB dead; overlay LDS) ----
  __syncthreads();                          // all waves done reading tA/tB
  for (int i = t; i < BIN12; i += 256) sm.h.lh[i] = 0;
  if (t == 0) lcnt = 0;
  __syncthreads();
  u32 k32[4][4];
  for (int i = 0; i < 4; ++i)
    for (int j = 0; j < 4; ++j) {
      k32[i][j] = fkey32(acc[i][j]);
      atomicAdd(&sm.h.lh[k32[i][j] >> 20], 1);
    }
  __syncthreads();
  const int BPT = BIN12 / 256;              // 16 bins/thread
  int base = t * BPT;
  int lsum = 0;
  for (int j = 0; j < BPT; ++j) lsum += sm.h.lh[base + j];
  sm.h.part[t] = lsum;
  __syncthreads();
  for (int off = 1; off < 256; off <<= 1) { // suffix scan over 256 partials
    int v = (t + off < 256) ? sm.h.part[t + off] : 0;
    __syncthreads();
    sm.h.part[t] += v;
    __syncthreads();
  }
  int Sab = sm.h.part[t] - lsum;            // count strictly above my bin range
  if (Sab < KM && Sab + lsum >= KM) {       // unique crossing thread
    int c = Sab;
    for (int j = BPT - 1; j >= 0; --j) {
      c += sm.h.lh[base + j];
      if (c >= KM) { Bbin = base + j; break; }
    }
  }
  __syncthreads();
  int Bb = Bbin;
  for (int i = 0; i < 4; ++i)
    for (int j = 0; j < 4; ++j)
      if ((int)(k32[i][j] >> 20) >= Bb) {
        int pos = atomicAdd(&lcnt, 1);      // LDS atomic; <= 4096 always
        int flat = (row0 + ra + i) * KKP + (col0 + rb + j);
        sm.h.lbuf[pos] = ((u64)k32[i][j] << 32) | (u32)(~(u32)flat);
      }
  __syncthreads();
  int blin = blockIdx.y * 8 + blockIdx.x;
  int n = lcnt;
  if (t == 0) mcnt_blk[b * 64 + blin] = n;
  for (int i = t; i < n; i += 256)
    mcand[((size_t)b * 64 + blin) * SEG_MC + i] = sm.h.lbuf[i];
}

// ---------------- exact match top-128 from per-block segments ----------------
// grid=2 (one block/batch). Wave-per-segment streaming (64 segments, ~150 keys
// each), radix-select + adaptive bitonic + decode.
__global__ __launch_bounds__(1024) void match_select(const u64* __restrict__ mcand,
                                                     const int* __restrict__ mcnt_blk,
                                                     const float* __restrict__ kp_loc,
                                                     float* __restrict__ out) {
  __shared__ int hist[NBINS];
  __shared__ u64 kbuf[CAP_COL];
  __shared__ int part[1024];
  __shared__ int mc[64];
  __shared__ int Bbin, colcnt;
  int b = blockIdx.x;
  int t = threadIdx.x;
  for (int i = t; i < NBINS; i += 1024) hist[i] = 0;
  if (t < 64) mc[t] = mcnt_blk[b * 64 + t];
  if (t == 0) { Bbin = 0; colcnt = 0; }
  __syncthreads();
  int wave = t >> 6, lane = t & 63;
  for (int s = wave; s < 64; s += 16) {
    int n = mc[s];
    const u64* seg = mcand + ((size_t)b * 64 + s) * SEG_MC;
    for (int i = lane; i < n; i += 64)
      atomicAdd(&hist[(u32)(seg[i] >> 50)], 1);   // key32 >> 18, 14 bits
  }
  __syncthreads();
  const int BPT = NBINS / 1024;
  int base = t * BPT;
  int lsum = 0;
  for (int j = 0; j < BPT; ++j) lsum += hist[base + j];
  part[t] = lsum;
  __syncthreads();
  for (int off = 1; off < 1024; off <<= 1) {   // suffix scan
    int v = (t + off < 1024) ? part[t + off] : 0;
    __syncthreads();
    part[t] += v;
    __syncthreads();
  }
  int Sab = part[t] - lsum;
  if (Sab < KM && Sab + lsum >= KM) {
    int c = Sab;
    for (int j = BPT - 1; j >= 0; --j) {
      c += hist[base + j];
      if (c >= KM) { Bbin = base + j; break; }
    }
  }
  __syncthreads();
  int Bb = Bbin;
  for (int s = wave; s < 64; s += 16) {
    int n = mc[s];
    const u64* seg = mcand + ((size_t)b * 64 + s) * SEG_MC;
    for (int i = lane; i < n; i += 64) {
      u64 kk = seg[i];
      if ((int)(kk >> 50) >= Bb) {
        int pos = atomicAdd(&colcnt, 1);
        if (pos < CAP_COL) kbuf[pos] = kk;
      }
    }
  }
  __syncthreads();
  int nc = colcnt; if (nc > CAP_COL) nc = CAP_COL;   // nc >= 128 by construction
  int need = nc > KM ? nc : KM;
  int npow = 1; while (npow < need) npow <<= 1;
  for (int i = t; i < npow; i += 1024) if (i >= nc) kbuf[i] = 0;
  __syncthreads();
  bitonicN(kbuf, t, npow, 1024);
  if (t < KM) {
    u64 key = kbuf[t];
    u32 flat = ~(u32)key;
    int i1 = (int)(flat >> 9), i2 = (int)(flat & 511);
    if (i1 >= KKP) { i1 = 0; i2 = 0; }  // pad guard
    int slot1 = b, slot2 = 2 + b;
    out[(b * 4 + 0) * KM + t] = kp_loc[(slot1 * 2 + 0) * KKP + i1];
    out[(b * 4 + 1) * KM + t] = kp_loc[(slot1 * 2 + 1) * KKP + i1];
    out[(b * 4 + 2) * KM + t] = kp_loc[(slot2 * 2 + 0) * KKP + i2];
    out[(b * 4 + 3) * KM + t] = kp_loc[(slot2 * 2 + 1) * KKP + i2];
  }
}

extern "C" void kernel_launch(void* const* d_in, const int* in_sizes, int n_in,
                              void* d_out, int out_size, void* d_ws, size_t ws_size,
                              hipStream_t stream) {
  (void)in_sizes; (void)n_in; (void)out_size; (void)ws_size;
  InPtrs P;
  P.rep[0][0] = (const float*)d_in[0];  P.rel[0][0] = (const float*)d_in[1];  P.desc[0][0] = (const float*)d_in[2];
  P.rep[0][1] = (const float*)d_in[3];  P.rel[0][1] = (const float*)d_in[4];  P.desc[0][1] = (const float*)d_in[5];
  P.rep[1][0] = (const float*)d_in[6];  P.rel[1][0] = (const float*)d_in[7];  P.desc[1][0] = (const float*)d_in[8];
  P.rep[1][1] = (const float*)d_in[9];  P.rel[1][1] = (const float*)d_in[10]; P.desc[1][1] = (const float*)d_in[11];

  char* ws = (char*)d_ws;
  // NO memset: every counter below is written unconditionally by its producer.
  size_t off = 0;
  int*   cnt_blk = (int*)(ws + off);  off += 4ULL * NBLK * 4;          // 11.5 KB
  int*   mcnt_blk= (int*)(ws + off);  off += 128 * 4;
  off = (off + 255) & ~255ULL;
  u64*   cand    = (u64*)(ws + off);  off += 4ULL * NTOT * 8;          // 5.9 MB
  float* kp_loc  = (float*)(ws + off); off += 4ULL * 2 * KKP * 4;
  int*   kp_level= (int*)(ws + off);  off += 4ULL * KKP * 4;
  int*   kp_p    = (int*)(ws + off);  off += 4ULL * KKP * 4;
  float* kp_score= (float*)(ws + off); off += 4ULL * KKP * 4;
  u64*   mcand   = (u64*)(ws + off);  off += 2ULL * 64 * SEG_MC * 8;   // 4 MB

  cand_kernel<<<dim3(NBLK, 4), 256, 0, stream>>>(P, cand, cnt_blk);
  kp_select<<<4, 1024, 0, stream>>>(cand, cnt_blk, kp_loc, kp_level, kp_p, kp_score);
  gemm_kernel<<<dim3(8, 8, 2), dim3(16, 16), 0, stream>>>(P, kp_level, kp_p, kp_score, mcand, mcnt_blk);
  match_select<<<2, 1024, 0, stream>>>(mcand, mcnt_blk, kp_loc, (float*)d_out);
}

// Round 5
// 404.829 us; speedup vs baseline: 1.2161x; 1.2161x over previous
//
#include <hip/hip_runtime.h>

typedef unsigned long long u64;
typedef unsigned int u32;

#define N0 147456   // 384*384
#define N1 36864    // 192*192
#define NTOT 184320 // = 720 * 256 exactly
#define NBLK 720    // cand blocks per slot
#define KKP 512
#define KM 128
#define CAP_CAND 16384
#define NBINS 16384
#define CAP_COL 2048
#define BIN12 4096      // gemm block-local histogram bins (key32 >> 20)
#define SEG_MC 4096     // per-gemm-block match-candidate segment (worst case = all 4096)

struct InPtrs {
  const float* rep[2][2];   // [img][level]
  const float* rel[2][2];
  const float* desc[2][2];
};

// ---------------- candidate generation ----------------
// slot = img*2 + b. Key = (score_bits<<32) | ~pixel_index  ->  descending sort
// == descending score, ties broken by LOWER index (matches lax.top_k).
// Block-aggregated append into a DENSE compacted array: LDS atomics + ONE
// global atomic per block. (R4 post-mortem: the private-segment + sparse-sweep
// alternative serialized kp_select on dependent HBM-miss latency, +110us.
// Dense compaction keeps kp_select's loads unconditional and pipelineable.)
__global__ __launch_bounds__(256) void cand_kernel(InPtrs P, u64* __restrict__ cand,
                                                   int* __restrict__ cnt) {
  __shared__ u64 buf[256];
  __shared__ int lcnt, gbase;
  int slot = blockIdx.y;
  int img = slot >> 1, b = slot & 1;
  int p = blockIdx.x * 256 + threadIdx.x;   // NTOT == 720*256, no tail
  if (threadIdx.x == 0) lcnt = 0;
  __syncthreads();
  int level, W, q, Npix;
  if (p < N0) { level = 0; W = 384; q = p; Npix = N0; }
  else        { level = 1; W = 192; q = p - N0; Npix = N1; }
  const float* rp = P.rep[img][level] + (size_t)b * Npix;
  const float* rl = P.rel[img][level] + (size_t)b * Npix;
  float v = rp[q];
  float m = sqrtf(v * rl[q]);
  bool ok = (m >= 0.7f);
  if (ok) {
    int y = q / W, x = q - y * W;   // square levels: H == W
    int y0 = (y > 0) ? y - 1 : y, y1 = (y < W - 1) ? y + 1 : y;
    int x0 = (x > 0) ? x - 1 : x, x1 = (x < W - 1) ? x + 1 : x;
    for (int yy = y0; yy <= y1 && ok; ++yy)
      for (int xx = x0; xx <= x1; ++xx)
        if (rp[yy * W + xx] > v) { ok = false; break; }
  }
  if (ok) {
    u32 sb = __float_as_uint(m);
    int pos = atomicAdd(&lcnt, 1);          // LDS atomic: cheap, per-CU
    buf[pos] = ((u64)sb << 32) | (u32)(~(u32)p);
  }
  __syncthreads();
  if (threadIdx.x == 0) gbase = lcnt ? atomicAdd(&cnt[slot * 16], lcnt) : 0;
  __syncthreads();
  int n = lcnt;
  if ((int)threadIdx.x < n) {
    int pos = gbase + (int)threadIdx.x;
    if (pos < CAP_CAND) cand[(size_t)slot * CAP_CAND + pos] = buf[threadIdx.x];
  }
}

// ------- adaptive bitonic sort of n (pow2) u64 keys in LDS, descending -------
__device__ inline void bitonicN(u64* k, int t, int n, int nthreads) {
  for (int size = 2; size <= n; size <<= 1) {
    for (int j = size >> 1; j > 0; j >>= 1) {
      __syncthreads();
      for (int i = t; i < n; i += nthreads) {
        int ixj = i ^ j;
        if (ixj > i) {
          u64 a = k[i], b = k[ixj];
          bool desc = ((i & size) == 0);
          if (desc ? (a < b) : (a > b)) { k[i] = b; k[ixj] = a; }
        }
      }
    }
  }
  __syncthreads();
}

// ---------------- keypoint top-512: radix-select + exact sort + decode ----------------
// Dense compacted input: every load unconditional and independent -> pipelined.
__global__ __launch_bounds__(1024) void kp_select(const u64* __restrict__ keys_all,
                                                  const int* __restrict__ cnt,
                                                  float* __restrict__ kp_loc,
                                                  int* __restrict__ kp_level,
                                                  int* __restrict__ kp_p,
                                                  float* __restrict__ kp_score) {
  __shared__ int hist[NBINS];
  __shared__ u64 kbuf[CAP_COL];
  __shared__ int part[1024];
  __shared__ int Bbin, colcnt;
  int slot = blockIdx.x;
  int t = threadIdx.x;
  const u64* keys = keys_all + (size_t)slot * CAP_CAND;
  int n = cnt[slot * 16]; if (n > CAP_CAND) n = CAP_CAND;
  for (int i = t; i < NBINS; i += 1024) hist[i] = 0;
  if (t == 0) { Bbin = 0; colcnt = 0; }
  __syncthreads();
  for (int i = t; i < n; i += 1024) {
    u32 bin = (u32)((keys[i] >> 41) & (NBINS - 1));
    atomicAdd(&hist[bin], 1);
  }
  __syncthreads();
  const int BPT = NBINS / 1024;
  int base = t * BPT;
  int lsum = 0;
  for (int j = 0; j < BPT; ++j) lsum += hist[base + j];
  part[t] = lsum;
  __syncthreads();
  for (int off = 1; off < 1024; off <<= 1) {   // suffix scan
    int v = (t + off < 1024) ? part[t + off] : 0;
    __syncthreads();
    part[t] += v;
    __syncthreads();
  }
  int Sab = part[t] - lsum;   // count strictly above my bin range
  if (Sab < KKP && Sab + lsum >= KKP) {
    int c = Sab;
    for (int j = BPT - 1; j >= 0; --j) {
      c += hist[base + j];
      if (c >= KKP) { Bbin = base + j; break; }
    }
  }
  __syncthreads();
  int Bb = Bbin;
  for (int i = t; i < n; i += 1024) {
    u64 kk = keys[i];
    if ((int)((kk >> 41) & (NBINS - 1)) >= Bb) {
      int pos = atomicAdd(&colcnt, 1);
      if (pos < CAP_COL) kbuf[pos] = kk;
    }
  }
  __syncthreads();
  int nc = colcnt; if (nc > CAP_COL) nc = CAP_COL;   // nc >= 512 by construction
  int npow = 1; while (npow < nc) npow <<= 1;        // adaptive sort width
  for (int i = t; i < npow; i += 1024) if (i >= nc) kbuf[i] = 0;
  __syncthreads();
  bitonicN(kbuf, t, npow, 1024);
  // fused decode (t < 512)
  if (t < KKP) {
    u64 key = kbuf[t];
    float s = __uint_as_float((u32)(key >> 32));
    u32 idx = ~(u32)key;
    int level, p, W, scale;
    if (idx < N0) { level = 0; p = (int)idx; W = 384; scale = 1; }
    else          { level = 1; p = (int)(idx - N0); W = 192; scale = 2; }
    if (p < 0 || p >= (level ? N1 : N0)) { p = 0; s = 0.f; }  // pad guard
    int y = p / W, x = p - y * W;
    kp_loc[(slot * 2 + 0) * KKP + t] = (float)(y * scale);
    kp_loc[(slot * 2 + 1) * KKP + t] = (float)(x * scale);
    kp_level[slot * KKP + t] = level;
    kp_p[slot * KKP + t] = p;
    kp_score[slot * KKP + t] = s;
  }
}

// ---------------- order-preserving float->u32 key ----------------
__device__ inline u32 fkey32(float v) {
  u32 bits = __float_as_uint(v);
  return (bits & 0x80000000u) ? ~bits : (bits | 0x80000000u);
}

// -------- fp32 GEMM (gather fused) + block-local top-128 candidate select --------
// Staging gathers descriptors DIRECTLY from desc: tA[c][kp] = desc_val * score,
// the exact fp32 expression the old gather_kernel stored to dAt, then the same
// accumulation loop -> bit-identical. Deletes the gather node + dAt round-trip.
// Output via per-block private segment (no atomics, no zeroed counters).
// Local-select exactness: an element with >=128 same-block elements in strictly
// higher bins has >=128 globally-larger keys, so the per-block bin-threshold
// superset contains the global top-128; final select is exact on full keys.
union GemmSmem {
  struct { float tA[128][68]; float tB[128][68]; } g;           // 69,632 B
  struct { int lh[BIN12]; int part[256]; u64 lbuf[4096]; } h;   // 49,408 B
};

__global__ __launch_bounds__(256) void gemm_kernel(InPtrs P,
                                                   const int* __restrict__ kp_level,
                                                   const int* __restrict__ kp_p,
                                                   const float* __restrict__ kp_score,
                                                   u64* __restrict__ mcand,
                                                   int* __restrict__ mcnt_blk) {
  __shared__ GemmSmem sm;
  __shared__ const float* basep[128];   // [0,64): A kps, [64,128): B kps
  __shared__ int strid[128];
  __shared__ float sco[128];
  __shared__ int Bbin, lcnt;
  int b = blockIdx.z;
  int row0 = blockIdx.y * 64, col0 = blockIdx.x * 64;
  int t = threadIdx.y * 16 + threadIdx.x;
  if (t < 128) {
    int isB = t >> 6, kk = t & 63;
    int slot = isB ? (2 + b) : b;                  // img0 slot=b, img1 slot=2+b
    int k = (isB ? col0 : row0) + kk;
    int lvl = kp_level[slot * KKP + k];
    int p = kp_p[slot * KKP + k];
    int img = slot >> 1;
    size_t HW = lvl ? N1 : N0;
    basep[t] = P.desc[img][lvl] + ((size_t)(slot & 1) * 128) * HW + p;
    strid[t] = (int)HW;
    sco[t] = kp_score[slot * KKP + k];
  }
  __syncthreads();
  // gather-staging: i = c*64+kp; lanes cover kp 0..63 (conflict-free LDS stores)
  for (int j = 0; j < 32; ++j) {
    int i = j * 256 + t;
    int kp = i & 63, c = i >> 6;
    sm.g.tA[c][kp] = basep[kp][(size_t)c * strid[kp]] * sco[kp];
  }
  for (int j = 0; j < 32; ++j) {
    int i = j * 256 + t;
    int kp = i & 63, c = i >> 6;
    sm.g.tB[c][kp] = basep[64 + kp][(size_t)c * strid[64 + kp]] * sco[64 + kp];
  }
  __syncthreads();
  float acc[4][4] = {};
  int ra = threadIdx.y * 4, rb = threadIdx.x * 4;
  for (int k = 0; k < 128; ++k) {
    float4 a4 = *(const float4*)&sm.g.tA[k][ra];
    float4 b4 = *(const float4*)&sm.g.tB[k][rb];
    float a[4] = {a4.x, a4.y, a4.z, a4.w};
    float bb[4] = {b4.x, b4.y, b4.z, b4.w};
    for (int i = 0; i < 4; ++i)
      for (int j = 0; j < 4; ++j)
        acc[i][j] += a[i] * bb[j];
  }
  // ---- block-local select (tA/tB dead; overlay LDS) ----
  __syncthreads();                          // all waves done reading tA/tB
  for (int i = t; i < BIN12; i += 256) sm.h.lh[i] = 0;
  if (t == 0) lcnt = 0;
  __syncthreads();
  u32 k32[4][4];
  for (int i = 0; i < 4; ++i)
    for (int j = 0; j < 4; ++j) {
      k32[i][j] = fkey32(acc[i][j]);
      atomicAdd(&sm.h.lh[k32[i][j] >> 20], 1);
    }
  __syncthreads();
  const int BPT = BIN12 / 256;              // 16 bins/thread
  int base = t * BPT;
  int lsum = 0;
  for (int j = 0; j < BPT; ++j) lsum += sm.h.lh[base + j];
  sm.h.part[t] = lsum;
  __syncthreads();
  for (int off = 1; off < 256; off <<= 1) { // suffix scan over 256 partials
    int v = (t + off < 256) ? sm.h.part[t + off] : 0;
    __syncthreads();
    sm.h.part[t] += v;
    __syncthreads();
  }
  int Sab = sm.h.part[t] - lsum;            // count strictly above my bin range
  if (Sab < KM && Sab + lsum >= KM) {       // unique crossing thread
    int c = Sab;
    for (int j = BPT - 1; j >= 0; --j) {
      c += sm.h.lh[base + j];
      if (c >= KM) { Bbin = base + j; break; }
    }
  }
  __syncthreads();
  int Bb = Bbin;
  for (int i = 0; i < 4; ++i)
    for (int j = 0; j < 4; ++j)
      if ((int)(k32[i][j] >> 20) >= Bb) {
        int pos = atomicAdd(&lcnt, 1);      // LDS atomic; <= 4096 always
        int flat = (row0 + ra + i) * KKP + (col0 + rb + j);
        sm.h.lbuf[pos] = ((u64)k32[i][j] << 32) | (u32)(~(u32)flat);
      }
  __syncthreads();
  int blin = blockIdx.y * 8 + blockIdx.x;
  int n = lcnt;
  if (t == 0) mcnt_blk[b * 64 + blin] = n;
  for (int i = t; i < n; i += 256)
    mcand[((size_t)b * 64 + blin) * SEG_MC + i] = sm.h.lbuf[i];
}

// ---------------- exact match top-128 from per-block segments ----------------
// grid=2 (one block/batch). Wave-per-segment streaming (64 segments, ~150 keys
// each, dense within segment), radix-select + adaptive bitonic + decode.
__global__ __launch_bounds__(1024) void match_select(const u64* __restrict__ mcand,
                                                     const int* __restrict__ mcnt_blk,
                                                     const float* __restrict__ kp_loc,
                                                     float* __restrict__ out) {
  __shared__ int hist[NBINS];
  __shared__ u64 kbuf[CAP_COL];
  __shared__ int part[1024];
  __shared__ int mc[64];
  __shared__ int Bbin, colcnt;
  int b = blockIdx.x;
  int t = threadIdx.x;
  for (int i = t; i < NBINS; i += 1024) hist[i] = 0;
  if (t < 64) mc[t] = mcnt_blk[b * 64 + t];
  if (t == 0) { Bbin = 0; colcnt = 0; }
  __syncthreads();
  int wave = t >> 6, lane = t & 63;
  for (int s = wave; s < 64; s += 16) {
    int n = mc[s];
    const u64* seg = mcand + ((size_t)b * 64 + s) * SEG_MC;
    for (int i = lane; i < n; i += 64)
      atomicAdd(&hist[(u32)(seg[i] >> 50)], 1);   // key32 >> 18, 14 bits
  }
  __syncthreads();
  const int BPT = NBINS / 1024;
  int base = t * BPT;
  int lsum = 0;
  for (int j = 0; j < BPT; ++j) lsum += hist[base + j];
  part[t] = lsum;
  __syncthreads();
  for (int off = 1; off < 1024; off <<= 1) {   // suffix scan
    int v = (t + off < 1024) ? part[t + off] : 0;
    __syncthreads();
    part[t] += v;
    __syncthreads();
  }
  int Sab = part[t] - lsum;
  if (Sab < KM && Sab + lsum >= KM) {
    int c = Sab;
    for (int j = BPT - 1; j >= 0; --j) {
      c += hist[base + j];
      if (c >= KM) { Bbin = base + j; break; }
    }
  }
  __syncthreads();
  int Bb = Bbin;
  for (int s = wave; s < 64; s += 16) {
    int n = mc[s];
    const u64* seg = mcand + ((size_t)b * 64 + s) * SEG_MC;
    for (int i = lane; i < n; i += 64) {
      u64 kk = seg[i];
      if ((int)(kk >> 50) >= Bb) {
        int pos = atomicAdd(&colcnt, 1);
        if (pos < CAP_COL) kbuf[pos] = kk;
      }
    }
  }
  __syncthreads();
  int nc = colcnt; if (nc > CAP_COL) nc = CAP_COL;   // nc >= 128 by construction
  int need = nc > KM ? nc : KM;
  int npow = 1; while (npow < need) npow <<= 1;
  for (int i = t; i < npow; i += 1024) if (i >= nc) kbuf[i] = 0;
  __syncthreads();
  bitonicN(kbuf, t, npow, 1024);
  if (t < KM) {
    u64 key = kbuf[t];
    u32 flat = ~(u32)key;
    int i1 = (int)(flat >> 9), i2 = (int)(flat & 511);
    if (i1 >= KKP) { i1 = 0; i2 = 0; }  // pad guard
    int slot1 = b, slot2 = 2 + b;
    out[(b * 4 + 0) * KM + t] = kp_loc[(slot1 * 2 + 0) * KKP + i1];
    out[(b * 4 + 1) * KM + t] = kp_loc[(slot1 * 2 + 1) * KKP + i1];
    out[(b * 4 + 2) * KM + t] = kp_loc[(slot2 * 2 + 0) * KKP + i2];
    out[(b * 4 + 3) * KM + t] = kp_loc[(slot2 * 2 + 1) * KKP + i2];
  }
}

extern "C" void kernel_launch(void* const* d_in, const int* in_sizes, int n_in,
                              void* d_out, int out_size, void* d_ws, size_t ws_size,
                              hipStream_t stream) {
  (void)in_sizes; (void)n_in; (void)out_size; (void)ws_size;
  InPtrs P;
  P.rep[0][0] = (const float*)d_in[0];  P.rel[0][0] = (const float*)d_in[1];  P.desc[0][0] = (const float*)d_in[2];
  P.rep[0][1] = (const float*)d_in[3];  P.rel[0][1] = (const float*)d_in[4];  P.desc[0][1] = (const float*)d_in[5];
  P.rep[1][0] = (const float*)d_in[6];  P.rel[1][0] = (const float*)d_in[7];  P.desc[1][0] = (const float*)d_in[8];
  P.rep[1][1] = (const float*)d_in[9];  P.rel[1][1] = (const float*)d_in[10]; P.desc[1][1] = (const float*)d_in[11];

  char* ws = (char*)d_ws;
  // counters: each slot's counter on its own 64B cacheline (stride-16 ints)
  int*   cnt_cand = (int*)(ws + 0);       // cnt_cand[slot*16], 4 slots -> 256B
  int*   mcnt_blk = (int*)(ws + 1024);    // 128 ints, written unconditionally (no zero)
  size_t off = 2048;
  u64*   cand    = (u64*)(ws + off);  off += 4ULL * CAP_CAND * 8;     // 512 KB
  float* kp_loc  = (float*)(ws + off); off += 4ULL * 2 * KKP * 4;
  int*   kp_level= (int*)(ws + off);  off += 4ULL * KKP * 4;
  int*   kp_p    = (int*)(ws + off);  off += 4ULL * KKP * 4;
  float* kp_score= (float*)(ws + off); off += 4ULL * KKP * 4;
  u64*   mcand   = (u64*)(ws + off);  off += 2ULL * 64 * SEG_MC * 8;  // 4 MB

  // zero candidate counters only (256B used; 1KB for alignment safety)
  hipMemsetAsync(d_ws, 0, 1024, stream);

  cand_kernel<<<dim3(NBLK, 4), 256, 0, stream>>>(P, cand, cnt_cand);
  kp_select<<<4, 1024, 0, stream>>>(cand, cnt_cand, kp_loc, kp_level, kp_p, kp_score);
  gemm_kernel<<<dim3(8, 8, 2), dim3(16, 16), 0, stream>>>(P, kp_level, kp_p, kp_score, mcand, mcnt_blk);
  match_select<<<2, 1024, 0, stream>>>(mcand, mcnt_blk, kp_loc, (float*)d_out);
}